// Round 13
// baseline (158.769 us; speedup 1.0000x reference)
//
#include <hip/hip_runtime.h>
#include <stdint.h>

#define DEVI __device__ __forceinline__

typedef __attribute__((ext_vector_type(8))) short bf16x8;
typedef __attribute__((ext_vector_type(4))) float floatx4;
typedef __attribute__((ext_vector_type(16))) float floatx16;

constexpr int Bb = 8, Ss = 1024, Ee = 1024, Hh = 16, HSs = 64;
constexpr int Mq = Bb * Ss;         // 8192
constexpr int Nqkv = 3 * Hh * HSs;  // 3072
constexpr int Kd = Ee;              // 1024

DEVI unsigned short f2bf(float x) {
  union { float f; uint32_t u; } v; v.f = x;
  uint32_t r = v.u + 0x7FFFu + ((v.u >> 16) & 1u);
  return (unsigned short)(r >> 16);
}

// native packed f32->bf16 (RNE, same rounding as f2bf): dst.lo=a, dst.hi=b
DEVI uint32_t cvtpk(float a, float b) {
  uint32_t r;
  asm("v_cvt_pk_bf16_f32 %0, %1, %2" : "=v"(r) : "v"(a), "v"(b));
  return r;
}

DEVI bf16x8 mkfrag(uint32_t a, uint32_t b, uint32_t c, uint32_t d) {
  union { uint32_t u[4]; bf16x8 v; } x;
  x.u[0] = a; x.u[1] = b; x.u[2] = c; x.u[3] = d;
  return x.v;
}

DEVI floatx4 mfma16(bf16x8 a, bf16x8 b, floatx4 c) {
  return __builtin_amdgcn_mfma_f32_16x16x32_bf16(a, b, c, 0, 0, 0);
}
DEVI floatx16 mfma32(bf16x8 a, bf16x8 b, floatx16 c) {
  return __builtin_amdgcn_mfma_f32_32x32x16_bf16(a, b, c, 0, 0, 0);
}

// global -> LDS direct copy, 16B per lane. LDS dest is wave-uniform base + lane*16.
DEVI void gload_lds16(const void* g, void* l) {
  __builtin_amdgcn_global_load_lds(
      (const __attribute__((address_space(1))) uint32_t*)(uintptr_t)g,
      (__attribute__((address_space(3))) uint32_t*)(uint32_t)(uintptr_t)l,
      16, 0, 0);
}

// ---------- converts: Wproj cast + Wqkv transpose-cast (x-cast fused into GEMM) --
// blocks [0,1024): Wproj cast; [1024,1792): Wqkv transpose.
// Wq/Wk/Wv [H][E][HS] fp32 -> Wqkv_t [3*H*HS][E] bf16, Wq scaled by 0.125*log2(e).
__global__ void cvt_fused(const float* __restrict__ Wproj,
                          const float* __restrict__ Wq, const float* __restrict__ Wk,
                          const float* __restrict__ Wv,
                          unsigned short* __restrict__ wprojb,
                          unsigned short* __restrict__ wqkvb) {
  __shared__ float tile[64][65];
  const int bid = blockIdx.x;
  if (bid < 1024) {  // block-uniform branch
    const int i = (bid * 256 + threadIdx.x) * 4;
    float4 v = *(const float4*)&Wproj[i];
    ushort4 o;
    o.x = f2bf(v.x); o.y = f2bf(v.y); o.z = f2bf(v.z); o.w = f2bf(v.w);
    *(ushort4*)(void*)&wprojb[i] = o;
    return;
  }
  const int idx = bid - 1024;       // 0..767
  const int k0 = (idx & 15) * 64;
  const int hh = idx >> 4;          // qkv*16 + h
  const int qkv = hh >> 4, h = hh & 15;
  const float* W = (qkv == 0) ? Wq : ((qkv == 1) ? Wk : Wv);
  const float scale = (qkv == 0) ? (0.125f * 1.44269504f) : 1.0f;
  const float* src = W + (size_t)h * Ee * HSs;
  const int c = threadIdx.x & 63, r4 = threadIdx.x >> 6;
#pragma unroll
  for (int rr = 0; rr < 16; ++rr) {
    int row = rr * 4 + r4;
    tile[row][c] = src[(size_t)(k0 + row) * HSs + c] * scale;
  }
  __syncthreads();
  const int base_n = qkv * 1024 + h * 64;
#pragma unroll
  for (int rr = 0; rr < 16; ++rr) {
    int hs = rr * 4 + r4;
    wqkvb[(size_t)(base_n + hs) * Kd + k0 + c] = f2bf(tile[c][hs]);
  }
}

// ---------- QKV GEMM: r2/r9 body with FUSED fp32->bf16 A-staging ----------
// A read directly from fp32 x: global float4 x2 -> cvt_pk -> ds_write_b128 at
// the EXACT addresses gload_lds used (same swizzle, same layout -> read side
// unchanged). B stays gload_lds. Cast VALU hides in the existing barrier stalls.
// Scatter epilogue to Q/K (bf16 [B,H,S,64]) and V transposed (bf16 [B,H,64,S]).
__global__ __launch_bounds__(256, 2) void gemm_qkv(
    const float* __restrict__ X, const unsigned short* __restrict__ Bt,
    unsigned short* __restrict__ Qb, unsigned short* __restrict__ Kb,
    unsigned short* __restrict__ Vtb, int Kdim) {
  __shared__ __align__(16) unsigned short As[128 * 64];
  __shared__ __align__(16) unsigned short Bs[128 * 64];
  const int tid = threadIdx.x;
  const int lane = tid & 63;
  const int wid = tid >> 6;
  const int wm = wid >> 1, wn = wid & 1;
  const int m0 = blockIdx.y * 128;
  const int n0 = blockIdx.x * 128;

  floatx4 acc[4][4];
#pragma unroll
  for (int i = 0; i < 4; ++i)
#pragma unroll
    for (int j = 0; j < 4; ++j) acc[i][j] = (floatx4)0.f;

  const int srow = lane >> 3;             // row within 8-row group
  const int schunk = (lane & 7) ^ srow;   // pre-swizzled source chunk (G21)

  for (int kt = 0; kt < Kdim; kt += 64) {
    // A: fp32 chunk loads to regs (issued first, in flight)
    float4 xr[4][2];
#pragma unroll
    for (int j = 0; j < 4; ++j) {
      const int g = wid * 4 + j;
      const int row = g * 8 + srow;
      const float* src = X + (size_t)(m0 + row) * Kdim + kt + schunk * 8;
      xr[j][0] = *(const float4*)src;
      xr[j][1] = *(const float4*)(src + 4);
    }
    // B: direct global->LDS
#pragma unroll
    for (int j = 0; j < 4; ++j) {
      const int g = wid * 4 + j;
      const int row = g * 8 + srow;
      gload_lds16(Bt + (size_t)(n0 + row) * Kdim + kt + schunk * 8, &Bs[g * 8 * 64]);
    }
    // A: cast + LDS write (same dest addresses gload_lds would have used)
#pragma unroll
    for (int j = 0; j < 4; ++j) {
      const int g = wid * 4 + j;
      const uint32_t w0 = cvtpk(xr[j][0].x, xr[j][0].y);
      const uint32_t w1 = cvtpk(xr[j][0].z, xr[j][0].w);
      const uint32_t w2 = cvtpk(xr[j][1].x, xr[j][1].y);
      const uint32_t w3 = cvtpk(xr[j][1].z, xr[j][1].w);
      *(bf16x8*)(void*)&As[g * 512 + lane * 8] = mkfrag(w0, w1, w2, w3);
    }
    __syncthreads();
#pragma unroll
    for (int kk = 0; kk < 2; ++kk) {
      const int c = kk * 4 + (lane >> 4);
      bf16x8 af[4], bf[4];
#pragma unroll
      for (int i = 0; i < 4; ++i) {
        const int ra = wm * 64 + i * 16 + (lane & 15);
        af[i] = *(const bf16x8*)&As[ra * 64 + ((c ^ (ra & 7)) << 3)];
        const int rb = wn * 64 + i * 16 + (lane & 15);
        bf[i] = *(const bf16x8*)&Bs[rb * 64 + ((c ^ (rb & 7)) << 3)];
      }
#pragma unroll
      for (int i = 0; i < 4; ++i)
#pragma unroll
        for (int j = 0; j < 4; ++j) acc[i][j] = mfma16(af[i], bf[j], acc[i][j]);
    }
    __syncthreads();
  }

  const int mrow0 = m0 + wm * 64 + ((lane >> 4) << 2);
  const int ncol0 = n0 + wn * 64 + (lane & 15);
#pragma unroll
  for (int i = 0; i < 4; ++i) {
#pragma unroll
    for (int j = 0; j < 4; ++j) {
      const int n = ncol0 + j * 16;
      const int qkv = n >> 10;
      const int h = (n & 1023) >> 6;
      const int hs = n & 63;
#pragma unroll
      for (int r = 0; r < 4; ++r) {
        const int m = mrow0 + i * 16 + r;
        const int b = m >> 10, s = m & 1023;
        const unsigned short bv = f2bf(acc[i][j][r]);
        if (qkv == 0)
          Qb[(((size_t)b * Hh + h) * Ss + s) * HSs + hs] = bv;
        else if (qkv == 1)
          Kb[(((size_t)b * Hh + h) * Ss + s) * HSs + hs] = bv;
        else
          Vtb[(((size_t)b * Hh + h) * HSs + hs) * Ss + s] = bv;
      }
    }
  }
}

// ---------- proj GEMM: round-2/round-9 body verbatim ----------
// C[M][N] = A[M][K] * Bt[N][K]^T + bias, fp32 out.
__global__ __launch_bounds__(256, 2) void gemm_proj(
    const unsigned short* __restrict__ A, const unsigned short* __restrict__ Bt,
    float* __restrict__ Out, const float* __restrict__ bias, int Ndim, int Kdim) {
  __shared__ __align__(16) unsigned short As[128 * 64];
  __shared__ __align__(16) unsigned short Bs[128 * 64];
  const int tid = threadIdx.x;
  const int lane = tid & 63;
  const int wid = tid >> 6;
  const int wm = wid >> 1, wn = wid & 1;
  const int m0 = blockIdx.y * 128;
  const int n0 = blockIdx.x * 128;

  floatx4 acc[4][4];
#pragma unroll
  for (int i = 0; i < 4; ++i)
#pragma unroll
    for (int j = 0; j < 4; ++j) acc[i][j] = (floatx4)0.f;

  const int srow = lane >> 3;             // row within 8-row group
  const int schunk = (lane & 7) ^ srow;   // pre-swizzled source chunk (G21)

  for (int kt = 0; kt < Kdim; kt += 64) {
#pragma unroll
    for (int j = 0; j < 4; ++j) {
      const int g = wid * 4 + j;
      const int row = g * 8 + srow;
      gload_lds16(A + (size_t)(m0 + row) * Kdim + kt + schunk * 8, &As[g * 8 * 64]);
      gload_lds16(Bt + (size_t)(n0 + row) * Kdim + kt + schunk * 8, &Bs[g * 8 * 64]);
    }
    __syncthreads();
#pragma unroll
    for (int kk = 0; kk < 2; ++kk) {
      const int c = kk * 4 + (lane >> 4);
      bf16x8 af[4], bf[4];
#pragma unroll
      for (int i = 0; i < 4; ++i) {
        const int ra = wm * 64 + i * 16 + (lane & 15);
        af[i] = *(const bf16x8*)&As[ra * 64 + ((c ^ (ra & 7)) << 3)];
        const int rb = wn * 64 + i * 16 + (lane & 15);
        bf[i] = *(const bf16x8*)&Bs[rb * 64 + ((c ^ (rb & 7)) << 3)];
      }
#pragma unroll
      for (int i = 0; i < 4; ++i)
#pragma unroll
        for (int j = 0; j < 4; ++j) acc[i][j] = mfma16(af[i], bf[j], acc[i][j]);
    }
    __syncthreads();
  }

  const int mrow0 = m0 + wm * 64 + ((lane >> 4) << 2);
  const int ncol0 = n0 + wn * 64 + (lane & 15);
#pragma unroll
  for (int j = 0; j < 4; ++j) {
    const int n = ncol0 + j * 16;
    const float bj = bias[n];
#pragma unroll
    for (int i = 0; i < 4; ++i) {
#pragma unroll
      for (int r = 0; r < 4; ++r) {
        const int m = mrow0 + i * 16 + r;
        Out[(size_t)m * Ndim + n] = acc[i][j][r] + bj;
      }
    }
  }
}

// ---------- flash attention (causal), swapped-operand 32x32 structure ----------
// Q [B*H][S][64] (pre-scaled by 0.125*log2e), K [B*H][S][64], Vt [B*H][64][S]
// QBLK=256 (8 waves), tri-buffered K/V, depth-2 prefetch, counted vmcnt,
// T13 defer-max, T12 native cvt_pk P-pack with 2-shfl half-exchange.
// 1D grid, XCD-grouped: all 4 q-blocks of one head share an XCD; heavy-q first.
// O -> [B][S][H*64] bf16
__global__ __launch_bounds__(512, 4) void attn(
    const unsigned short* __restrict__ Qb, const unsigned short* __restrict__ Kb,
    const unsigned short* __restrict__ Vtb, unsigned short* __restrict__ Ob) {
  __shared__ __align__(16) unsigned short Ks[3][64 * 64];
  __shared__ __align__(16) unsigned short Vs[3][64 * 64];

  const int tid = threadIdx.x;
  const int lane = tid & 63;
  const int wid = tid >> 6;          // 0..7
  const int ln = lane & 31;
  const int hi = lane >> 5;
  const int bh = blockIdx.x & 127;   // wgid%8 == bh%8 -> same head stays on one XCD
  const int qs = blockIdx.x >> 7;    // 0..3
  const int q0 = (3 - qs) * 256;     // heavy blocks dispatched first
  const int bI = bh >> 4, hI = bh & 15;
  const unsigned short* Qp = Qb + (size_t)bh * Ss * HSs;
  const unsigned short* Kp = Kb + (size_t)bh * Ss * HSs;
  const unsigned short* Vp = Vtb + (size_t)bh * HSs * Ss;
  const int qw = q0 + wid * 32;
  const int q = qw + ln;  // this lane's q row (lane and lane^32 share q)

  // Q as B-operand: qf[kc] holds Q[d = 16*kc + 8*hi + e][q], e=0..7
  bf16x8 qf[4];
#pragma unroll
  for (int kc = 0; kc < 4; ++kc)
    qf[kc] = *(const bf16x8*)&Qp[(size_t)q * 64 + kc * 16 + hi * 8];

  floatx16 oacc[2];
  oacc[0] = (floatx16)0.f;
  oacc[1] = (floatx16)0.f;
  float mrow = -3.0e38f, lrow = 0.f;

  const int srow = lane >> 3;
  const int schunk = (lane & 7) ^ srow;
  const int nt = (q0 >> 6) + 4;

  // per wave: 1 K-row-group + 1 V-row-group (8 waves cover 64 rows each)
  auto stageKV = [&](int t, int b) {
    const int row = wid * 8 + srow;
    gload_lds16(Kp + (size_t)(t * 64 + row) * 64 + schunk * 8, &Ks[b][wid * 512]);
    gload_lds16(Vp + (size_t)row * Ss + t * 64 + schunk * 8, &Vs[b][wid * 512]);
  };

  // prologue: stage tiles 0,1 (4 loads/wave); wait tile0 (2 remain)
  stageKV(0, 0);
  stageKV(1, 1);
  asm volatile("s_waitcnt vmcnt(2)" ::: "memory");
  __builtin_amdgcn_s_barrier();

  for (int t = 0; t < nt; ++t) {
    const int cur = t % 3;
    const bool pf = (t + 2 < nt);
    if (pf) stageKV(t + 2, (t + 2) % 3);
    const int t0 = t * 64;

    if (t0 <= qw + 31) {  // wave has at least one unmasked row in this tile
      const unsigned short* Kc = Ks[cur];
      const unsigned short* Vc = Vs[cur];
      // S^T tiles: sc[tt][r] = S[t = t0+32*tt+(r&3)+8*(r>>2)+4*hi][q]
      floatx16 sc[2];
#pragma unroll
      for (int tt = 0; tt < 2; ++tt) {
        floatx16 s = (floatx16)0.f;
        __builtin_amdgcn_s_setprio(1);
#pragma unroll
        for (int kc = 0; kc < 4; ++kc) {
          const int row = tt * 32 + ln;
          bf16x8 kf = *(const bf16x8*)&Kc[row * 64 + ((((kc << 1) | hi) ^ (ln & 7)) << 3)];
          s = mfma32(kf, qf[kc], s);
        }
        __builtin_amdgcn_s_setprio(0);
        sc[tt] = s;
      }
      if (t0 + 63 > qw) {  // diagonal region: mask t > q
#pragma unroll
        for (int tt = 0; tt < 2; ++tt)
#pragma unroll
          for (int r = 0; r < 16; ++r) {
            const int tg = t0 + tt * 32 + (r & 3) + 8 * (r >> 2) + 4 * hi;
            if (tg > q) sc[tt][r] = -1e30f;
          }
      }
      // online softmax — lane-local except one shfl_xor(32) per reduce.
      // T13 defer-max: keep old running max (skip O/l rescale) while the
      // tile max stays within +8 of it; P then bounded by 2^8 (exact math).
      float mx = sc[0][0];
#pragma unroll
      for (int tt = 0; tt < 2; ++tt)
#pragma unroll
        for (int r = 0; r < 16; ++r) mx = fmaxf(mx, sc[tt][r]);
      mx = fmaxf(mx, __shfl_xor(mx, 32));
      if (!__all(mx - mrow <= 8.0f)) {
        const float mnew = fmaxf(mrow, mx);
        const float scal = __builtin_amdgcn_exp2f(mrow - mnew);
        mrow = mnew;
        lrow *= scal;
#pragma unroll
        for (int dt = 0; dt < 2; ++dt)
#pragma unroll
          for (int r = 0; r < 16; ++r) oacc[dt][r] *= scal;
      }
      float ss = 0.f;
#pragma unroll
      for (int tt = 0; tt < 2; ++tt)
#pragma unroll
        for (int r = 0; r < 16; ++r) {
          const float p = __builtin_amdgcn_exp2f(sc[tt][r] - mrow);
          sc[tt][r] = p;
          ss += p;
        }
      ss += __shfl_xor(ss, 32);
      lrow += ss;

      // P (S^T regs) -> PV B-fragments: native v_cvt_pk_bf16_f32 (same RNE as
      // f2bf) + 2-shfl half-exchange: send s=hi?w0:w2 so one shfl_xor(32)
      // serves both directions (lo needs partner w0/w1, hi needs partner w2/w3).
      bf16x8 pf_[4];
#pragma unroll
      for (int tt = 0; tt < 2; ++tt)
#pragma unroll
        for (int fb = 0; fb < 2; ++fb) {
          const int b = fb * 8;
          const uint32_t w0 = cvtpk(sc[tt][b + 0], sc[tt][b + 1]);
          const uint32_t w1 = cvtpk(sc[tt][b + 2], sc[tt][b + 3]);
          const uint32_t w2 = cvtpk(sc[tt][b + 4], sc[tt][b + 5]);
          const uint32_t w3 = cvtpk(sc[tt][b + 6], sc[tt][b + 7]);
          const uint32_t s0 = hi ? w0 : w2;
          const uint32_t s1 = hi ? w1 : w3;
          const uint32_t r0 = (uint32_t)__shfl_xor((int)s0, 32);
          const uint32_t r1 = (uint32_t)__shfl_xor((int)s1, 32);
          pf_[tt * 2 + fb] = mkfrag(hi ? r0 : w0, hi ? r1 : w1, hi ? w2 : r0, hi ? w3 : r1);
        }
      // PV: O^T[d][q] += V^T x P^T
#pragma unroll
      for (int dt = 0; dt < 2; ++dt) {
        const int row = dt * 32 + ln;
        __builtin_amdgcn_s_setprio(1);
#pragma unroll
        for (int kc = 0; kc < 4; ++kc) {
          bf16x8 vf = *(const bf16x8*)&Vc[row * 64 + ((((kc << 1) | hi) ^ (ln & 7)) << 3)];
          oacc[dt] = mfma32(vf, pf_[kc], oacc[dt]);
        }
        __builtin_amdgcn_s_setprio(0);
      }
    }

    if (pf) { asm volatile("s_waitcnt vmcnt(2)" ::: "memory"); }
    else    { asm volatile("s_waitcnt vmcnt(0)" ::: "memory"); }
    __builtin_amdgcn_s_barrier();
  }

  // epilogue: lane holds O[q][d] for d = 32*dt + 8*g4 + 4*hi + 0..3
  const float inv = 1.0f / lrow;
  unsigned short* Op = Ob + ((size_t)bI * Ss + q) * Ee + hI * 64;
#pragma unroll
  for (int dt = 0; dt < 2; ++dt)
#pragma unroll
    for (int g4 = 0; g4 < 4; ++g4) {
      ushort4 o;
      o.x = f2bf(oacc[dt][g4 * 4 + 0] * inv);
      o.y = f2bf(oacc[dt][g4 * 4 + 1] * inv);
      o.z = f2bf(oacc[dt][g4 * 4 + 2] * inv);
      o.w = f2bf(oacc[dt][g4 * 4 + 3] * inv);
      *(ushort4*)(void*)&Op[dt * 32 + g4 * 8 + hi * 4] = o;
    }
}

extern "C" void kernel_launch(void* const* d_in, const int* in_sizes, int n_in,
                              void* d_out, int out_size, void* d_ws, size_t ws_size,
                              hipStream_t stream) {
  const float* x = (const float*)d_in[0];
  const float* Wq = (const float*)d_in[1];
  const float* Wk = (const float*)d_in[2];
  const float* Wv = (const float*)d_in[3];
  const float* Wproj = (const float*)d_in[4];
  const float* bproj = (const float*)d_in[5];
  float* out = (float*)d_out;

  char* ws = (char*)d_ws;
  unsigned short* wqkvb  = (unsigned short*)(ws + (16u << 20));    //  6 MiB
  unsigned short* wprojb = (unsigned short*)(ws + (22u << 20));    //  2 MiB
  unsigned short* Qb     = (unsigned short*)(ws + (24u << 20));    // 16 MiB
  unsigned short* Kb     = (unsigned short*)(ws + (40u << 20));    // 16 MiB
  unsigned short* Vtb    = (unsigned short*)(ws + (56u << 20));    // 16 MiB
  unsigned short* Obuf   = (unsigned short*)(ws + (72u << 20));    // 16 MiB (88 total)

  cvt_fused<<<1792, 256, 0, stream>>>(Wproj, Wq, Wk, Wv, wprojb, wqkvb);
  gemm_qkv<<<dim3(Nqkv / 128, Mq / 128), 256, 0, stream>>>(
      x, wqkvb, Qb, Kb, Vtb, Kd);
  attn<<<512, 512, 0, stream>>>(Qb, Kb, Vtb, Obuf);
  gemm_proj<<<dim3(Ee / 128, Mq / 128), 256, 0, stream>>>(
      Obuf, wprojb, out, bproj, Ee, Kd);
}

// Round 14
// 150.924 us; speedup vs baseline: 1.0520x; 1.0520x over previous
//
#include <hip/hip_runtime.h>
#include <stdint.h>

#define DEVI __device__ __forceinline__

typedef __attribute__((ext_vector_type(8))) short bf16x8;
typedef __attribute__((ext_vector_type(4))) float floatx4;
typedef __attribute__((ext_vector_type(16))) float floatx16;

constexpr int Bb = 8, Ss = 1024, Ee = 1024, Hh = 16, HSs = 64;
constexpr int Mq = Bb * Ss;         // 8192
constexpr int Nqkv = 3 * Hh * HSs;  // 3072
constexpr int Kd = Ee;              // 1024

DEVI unsigned short f2bf(float x) {
  union { float f; uint32_t u; } v; v.f = x;
  uint32_t r = v.u + 0x7FFFu + ((v.u >> 16) & 1u);
  return (unsigned short)(r >> 16);
}

// native packed f32->bf16 (RNE, same rounding as f2bf): dst.lo=a, dst.hi=b
DEVI uint32_t cvtpk(float a, float b) {
  uint32_t r;
  asm("v_cvt_pk_bf16_f32 %0, %1, %2" : "=v"(r) : "v"(a), "v"(b));
  return r;
}

DEVI bf16x8 mkfrag(uint32_t a, uint32_t b, uint32_t c, uint32_t d) {
  union { uint32_t u[4]; bf16x8 v; } x;
  x.u[0] = a; x.u[1] = b; x.u[2] = c; x.u[3] = d;
  return x.v;
}

DEVI floatx4 mfma16(bf16x8 a, bf16x8 b, floatx4 c) {
  return __builtin_amdgcn_mfma_f32_16x16x32_bf16(a, b, c, 0, 0, 0);
}
DEVI floatx16 mfma32(bf16x8 a, bf16x8 b, floatx16 c) {
  return __builtin_amdgcn_mfma_f32_32x32x16_bf16(a, b, c, 0, 0, 0);
}

// global -> LDS direct copy, 16B per lane. LDS dest is wave-uniform base + lane*16.
DEVI void gload_lds16(const void* g, void* l) {
  __builtin_amdgcn_global_load_lds(
      (const __attribute__((address_space(1))) uint32_t*)(uintptr_t)g,
      (__attribute__((address_space(3))) uint32_t*)(uint32_t)(uintptr_t)l,
      16, 0, 0);
}

// ---------- converts: ONE launch ----------
// blocks [0,8192): x cast; [8192,9216): Wproj cast; [9216,9984): Wqkv transpose.
// Wq/Wk/Wv [H][E][HS] fp32 -> Wqkv_t [3*H*HS][E] bf16, Wq scaled by 0.125*log2(e).
__global__ void cvt_fused(const float* __restrict__ x, const float* __restrict__ Wproj,
                          const float* __restrict__ Wq, const float* __restrict__ Wk,
                          const float* __restrict__ Wv,
                          unsigned short* __restrict__ xb, unsigned short* __restrict__ wprojb,
                          unsigned short* __restrict__ wqkvb) {
  __shared__ float tile[64][65];
  const int bid = blockIdx.x;
  if (bid < 9216) {  // block-uniform branch (no sync inside)
    const float* in; unsigned short* out; int i;
    if (bid < 8192) { in = x;     out = xb;     i = (bid * 256 + threadIdx.x) * 4; }
    else            { in = Wproj; out = wprojb; i = ((bid - 8192) * 256 + threadIdx.x) * 4; }
    float4 v = *(const float4*)&in[i];
    ushort4 o;
    o.x = f2bf(v.x); o.y = f2bf(v.y); o.z = f2bf(v.z); o.w = f2bf(v.w);
    *(ushort4*)(void*)&out[i] = o;
    return;
  }
  const int idx = bid - 9216;       // 0..767
  const int k0 = (idx & 15) * 64;
  const int hh = idx >> 4;          // qkv*16 + h
  const int qkv = hh >> 4, h = hh & 15;
  const float* W = (qkv == 0) ? Wq : ((qkv == 1) ? Wk : Wv);
  const float scale = (qkv == 0) ? (0.125f * 1.44269504f) : 1.0f;
  const float* src = W + (size_t)h * Ee * HSs;
  const int c = threadIdx.x & 63, r4 = threadIdx.x >> 6;
#pragma unroll
  for (int rr = 0; rr < 16; ++rr) {
    int row = rr * 4 + r4;
    tile[row][c] = src[(size_t)(k0 + row) * HSs + c] * scale;
  }
  __syncthreads();
  const int base_n = qkv * 1024 + h * 64;
#pragma unroll
  for (int rr = 0; rr < 16; ++rr) {
    int hs = rr * 4 + r4;
    wqkvb[(size_t)(base_n + hs) * Kd + k0 + c] = f2bf(tile[c][hs]);
  }
}

// ---------- QKV GEMM: exact round-2/round-9 body (measured ~79 us) ----------
// 128x128, 4 waves, single-buffer 32KB, 2 barriers/K-tile, lb(256,2).
// Scatter epilogue to Q/K (bf16 [B,H,S,64]) and V transposed (bf16 [B,H,64,S]).
__global__ __launch_bounds__(256, 2) void gemm_qkv(
    const unsigned short* __restrict__ A, const unsigned short* __restrict__ Bt,
    unsigned short* __restrict__ Qb, unsigned short* __restrict__ Kb,
    unsigned short* __restrict__ Vtb, int Kdim) {
  __shared__ __align__(16) unsigned short As[128 * 64];
  __shared__ __align__(16) unsigned short Bs[128 * 64];
  const int tid = threadIdx.x;
  const int lane = tid & 63;
  const int wid = tid >> 6;
  const int wm = wid >> 1, wn = wid & 1;
  const int m0 = blockIdx.y * 128;
  const int n0 = blockIdx.x * 128;

  floatx4 acc[4][4];
#pragma unroll
  for (int i = 0; i < 4; ++i)
#pragma unroll
    for (int j = 0; j < 4; ++j) acc[i][j] = (floatx4)0.f;

  const int srow = lane >> 3;             // row within 8-row group
  const int schunk = (lane & 7) ^ srow;   // pre-swizzled source chunk (G21)

  for (int kt = 0; kt < Kdim; kt += 64) {
#pragma unroll
    for (int j = 0; j < 4; ++j) {
      const int g = wid * 4 + j;
      const int row = g * 8 + srow;
      gload_lds16(A + (size_t)(m0 + row) * Kdim + kt + schunk * 8, &As[g * 8 * 64]);
      gload_lds16(Bt + (size_t)(n0 + row) * Kdim + kt + schunk * 8, &Bs[g * 8 * 64]);
    }
    __syncthreads();
#pragma unroll
    for (int kk = 0; kk < 2; ++kk) {
      const int c = kk * 4 + (lane >> 4);
      bf16x8 af[4], bf[4];
#pragma unroll
      for (int i = 0; i < 4; ++i) {
        const int ra = wm * 64 + i * 16 + (lane & 15);
        af[i] = *(const bf16x8*)&As[ra * 64 + ((c ^ (ra & 7)) << 3)];
        const int rb = wn * 64 + i * 16 + (lane & 15);
        bf[i] = *(const bf16x8*)&Bs[rb * 64 + ((c ^ (rb & 7)) << 3)];
      }
#pragma unroll
      for (int i = 0; i < 4; ++i)
#pragma unroll
        for (int j = 0; j < 4; ++j) acc[i][j] = mfma16(af[i], bf[j], acc[i][j]);
    }
    __syncthreads();
  }

  const int mrow0 = m0 + wm * 64 + ((lane >> 4) << 2);
  const int ncol0 = n0 + wn * 64 + (lane & 15);
#pragma unroll
  for (int i = 0; i < 4; ++i) {
#pragma unroll
    for (int j = 0; j < 4; ++j) {
      const int n = ncol0 + j * 16;
      const int qkv = n >> 10;
      const int h = (n & 1023) >> 6;
      const int hs = n & 63;
#pragma unroll
      for (int r = 0; r < 4; ++r) {
        const int m = mrow0 + i * 16 + r;
        const int b = m >> 10, s = m & 1023;
        const unsigned short bv = f2bf(acc[i][j][r]);
        if (qkv == 0)
          Qb[(((size_t)b * Hh + h) * Ss + s) * HSs + hs] = bv;
        else if (qkv == 1)
          Kb[(((size_t)b * Hh + h) * Ss + s) * HSs + hs] = bv;
        else
          Vtb[(((size_t)b * Hh + h) * HSs + hs) * Ss + s] = bv;
      }
    }
  }
}

// ---------- proj GEMM: round-2/round-9 body verbatim ----------
// C[M][N] = A[M][K] * Bt[N][K]^T + bias, fp32 out.
__global__ __launch_bounds__(256, 2) void gemm_proj(
    const unsigned short* __restrict__ A, const unsigned short* __restrict__ Bt,
    float* __restrict__ Out, const float* __restrict__ bias, int Ndim, int Kdim) {
  __shared__ __align__(16) unsigned short As[128 * 64];
  __shared__ __align__(16) unsigned short Bs[128 * 64];
  const int tid = threadIdx.x;
  const int lane = tid & 63;
  const int wid = tid >> 6;
  const int wm = wid >> 1, wn = wid & 1;
  const int m0 = blockIdx.y * 128;
  const int n0 = blockIdx.x * 128;

  floatx4 acc[4][4];
#pragma unroll
  for (int i = 0; i < 4; ++i)
#pragma unroll
    for (int j = 0; j < 4; ++j) acc[i][j] = (floatx4)0.f;

  const int srow = lane >> 3;             // row within 8-row group
  const int schunk = (lane & 7) ^ srow;   // pre-swizzled source chunk (G21)

  for (int kt = 0; kt < Kdim; kt += 64) {
#pragma unroll
    for (int j = 0; j < 4; ++j) {
      const int g = wid * 4 + j;
      const int row = g * 8 + srow;
      gload_lds16(A + (size_t)(m0 + row) * Kdim + kt + schunk * 8, &As[g * 8 * 64]);
      gload_lds16(Bt + (size_t)(n0 + row) * Kdim + kt + schunk * 8, &Bs[g * 8 * 64]);
    }
    __syncthreads();
#pragma unroll
    for (int kk = 0; kk < 2; ++kk) {
      const int c = kk * 4 + (lane >> 4);
      bf16x8 af[4], bf[4];
#pragma unroll
      for (int i = 0; i < 4; ++i) {
        const int ra = wm * 64 + i * 16 + (lane & 15);
        af[i] = *(const bf16x8*)&As[ra * 64 + ((c ^ (ra & 7)) << 3)];
        const int rb = wn * 64 + i * 16 + (lane & 15);
        bf[i] = *(const bf16x8*)&Bs[rb * 64 + ((c ^ (rb & 7)) << 3)];
      }
#pragma unroll
      for (int i = 0; i < 4; ++i)
#pragma unroll
        for (int j = 0; j < 4; ++j) acc[i][j] = mfma16(af[i], bf[j], acc[i][j]);
    }
    __syncthreads();
  }

  const int mrow0 = m0 + wm * 64 + ((lane >> 4) << 2);
  const int ncol0 = n0 + wn * 64 + (lane & 15);
#pragma unroll
  for (int j = 0; j < 4; ++j) {
    const int n = ncol0 + j * 16;
    const float bj = bias[n];
#pragma unroll
    for (int i = 0; i < 4; ++i) {
#pragma unroll
      for (int r = 0; r < 4; ++r) {
        const int m = mrow0 + i * 16 + r;
        Out[(size_t)m * Ndim + n] = acc[i][j][r] + bj;
      }
    }
  }
}

// ---------- flash attention (causal), swapped-operand 32x32 structure ----------
// Q [B*H][S][64] (pre-scaled by 0.125*log2e), K [B*H][S][64], Vt [B*H][64][S]
// QBLK=256 (8 waves), tri-buffered K/V, depth-2 prefetch, counted vmcnt,
// T13 defer-max, T12 native cvt_pk P-pack with 2-shfl half-exchange.
// 1D grid, XCD-grouped: all 4 q-blocks of one head share an XCD; heavy-q first.
// O -> [B][S][H*64] bf16
__global__ __launch_bounds__(512, 4) void attn(
    const unsigned short* __restrict__ Qb, const unsigned short* __restrict__ Kb,
    const unsigned short* __restrict__ Vtb, unsigned short* __restrict__ Ob) {
  __shared__ __align__(16) unsigned short Ks[3][64 * 64];
  __shared__ __align__(16) unsigned short Vs[3][64 * 64];

  const int tid = threadIdx.x;
  const int lane = tid & 63;
  const int wid = tid >> 6;          // 0..7
  const int ln = lane & 31;
  const int hi = lane >> 5;
  const int bh = blockIdx.x & 127;   // wgid%8 == bh%8 -> same head stays on one XCD
  const int qs = blockIdx.x >> 7;    // 0..3
  const int q0 = (3 - qs) * 256;     // heavy blocks dispatched first
  const int bI = bh >> 4, hI = bh & 15;
  const unsigned short* Qp = Qb + (size_t)bh * Ss * HSs;
  const unsigned short* Kp = Kb + (size_t)bh * Ss * HSs;
  const unsigned short* Vp = Vtb + (size_t)bh * HSs * Ss;
  const int qw = q0 + wid * 32;
  const int q = qw + ln;  // this lane's q row (lane and lane^32 share q)

  // Q as B-operand: qf[kc] holds Q[d = 16*kc + 8*hi + e][q], e=0..7
  bf16x8 qf[4];
#pragma unroll
  for (int kc = 0; kc < 4; ++kc)
    qf[kc] = *(const bf16x8*)&Qp[(size_t)q * 64 + kc * 16 + hi * 8];

  floatx16 oacc[2];
  oacc[0] = (floatx16)0.f;
  oacc[1] = (floatx16)0.f;
  float mrow = -3.0e38f, lrow = 0.f;

  const int srow = lane >> 3;
  const int schunk = (lane & 7) ^ srow;
  const int nt = (q0 >> 6) + 4;

  // per wave: 1 K-row-group + 1 V-row-group (8 waves cover 64 rows each)
  auto stageKV = [&](int t, int b) {
    const int row = wid * 8 + srow;
    gload_lds16(Kp + (size_t)(t * 64 + row) * 64 + schunk * 8, &Ks[b][wid * 512]);
    gload_lds16(Vp + (size_t)row * Ss + t * 64 + schunk * 8, &Vs[b][wid * 512]);
  };

  // prologue: stage tiles 0,1 (4 loads/wave); wait tile0 (2 remain)
  stageKV(0, 0);
  stageKV(1, 1);
  asm volatile("s_waitcnt vmcnt(2)" ::: "memory");
  __builtin_amdgcn_s_barrier();

  for (int t = 0; t < nt; ++t) {
    const int cur = t % 3;
    const bool pf = (t + 2 < nt);
    if (pf) stageKV(t + 2, (t + 2) % 3);
    const int t0 = t * 64;

    if (t0 <= qw + 31) {  // wave has at least one unmasked row in this tile
      const unsigned short* Kc = Ks[cur];
      const unsigned short* Vc = Vs[cur];
      // S^T tiles: sc[tt][r] = S[t = t0+32*tt+(r&3)+8*(r>>2)+4*hi][q]
      floatx16 sc[2];
#pragma unroll
      for (int tt = 0; tt < 2; ++tt) {
        floatx16 s = (floatx16)0.f;
        __builtin_amdgcn_s_setprio(1);
#pragma unroll
        for (int kc = 0; kc < 4; ++kc) {
          const int row = tt * 32 + ln;
          bf16x8 kf = *(const bf16x8*)&Kc[row * 64 + ((((kc << 1) | hi) ^ (ln & 7)) << 3)];
          s = mfma32(kf, qf[kc], s);
        }
        __builtin_amdgcn_s_setprio(0);
        sc[tt] = s;
      }
      if (t0 + 63 > qw) {  // diagonal region: mask t > q
#pragma unroll
        for (int tt = 0; tt < 2; ++tt)
#pragma unroll
          for (int r = 0; r < 16; ++r) {
            const int tg = t0 + tt * 32 + (r & 3) + 8 * (r >> 2) + 4 * hi;
            if (tg > q) sc[tt][r] = -1e30f;
          }
      }
      // online softmax — lane-local except one shfl_xor(32) per reduce.
      // T13 defer-max: keep old running max (skip O/l rescale) while the
      // tile max stays within +8 of it; P then bounded by 2^8 (exact math).
      float mx = sc[0][0];
#pragma unroll
      for (int tt = 0; tt < 2; ++tt)
#pragma unroll
        for (int r = 0; r < 16; ++r) mx = fmaxf(mx, sc[tt][r]);
      mx = fmaxf(mx, __shfl_xor(mx, 32));
      if (!__all(mx - mrow <= 8.0f)) {
        const float mnew = fmaxf(mrow, mx);
        const float scal = __builtin_amdgcn_exp2f(mrow - mnew);
        mrow = mnew;
        lrow *= scal;
#pragma unroll
        for (int dt = 0; dt < 2; ++dt)
#pragma unroll
          for (int r = 0; r < 16; ++r) oacc[dt][r] *= scal;
      }
      float ss = 0.f;
#pragma unroll
      for (int tt = 0; tt < 2; ++tt)
#pragma unroll
        for (int r = 0; r < 16; ++r) {
          const float p = __builtin_amdgcn_exp2f(sc[tt][r] - mrow);
          sc[tt][r] = p;
          ss += p;
        }
      ss += __shfl_xor(ss, 32);
      lrow += ss;

      // P (S^T regs) -> PV B-fragments: native v_cvt_pk_bf16_f32 (same RNE as
      // f2bf) + 2-shfl half-exchange: send s=hi?w0:w2 so one shfl_xor(32)
      // serves both directions (lo needs partner w0/w1, hi needs partner w2/w3).
      bf16x8 pf_[4];
#pragma unroll
      for (int tt = 0; tt < 2; ++tt)
#pragma unroll
        for (int fb = 0; fb < 2; ++fb) {
          const int b = fb * 8;
          const uint32_t w0 = cvtpk(sc[tt][b + 0], sc[tt][b + 1]);
          const uint32_t w1 = cvtpk(sc[tt][b + 2], sc[tt][b + 3]);
          const uint32_t w2 = cvtpk(sc[tt][b + 4], sc[tt][b + 5]);
          const uint32_t w3 = cvtpk(sc[tt][b + 6], sc[tt][b + 7]);
          const uint32_t s0 = hi ? w0 : w2;
          const uint32_t s1 = hi ? w1 : w3;
          const uint32_t r0 = (uint32_t)__shfl_xor((int)s0, 32);
          const uint32_t r1 = (uint32_t)__shfl_xor((int)s1, 32);
          pf_[tt * 2 + fb] = mkfrag(hi ? r0 : w0, hi ? r1 : w1, hi ? w2 : r0, hi ? w3 : r1);
        }
      // PV: O^T[d][q] += V^T x P^T
#pragma unroll
      for (int dt = 0; dt < 2; ++dt) {
        const int row = dt * 32 + ln;
        __builtin_amdgcn_s_setprio(1);
#pragma unroll
        for (int kc = 0; kc < 4; ++kc) {
          bf16x8 vf = *(const bf16x8*)&Vc[row * 64 + ((((kc << 1) | hi) ^ (ln & 7)) << 3)];
          oacc[dt] = mfma32(vf, pf_[kc], oacc[dt]);
        }
        __builtin_amdgcn_s_setprio(0);
      }
    }

    if (pf) { asm volatile("s_waitcnt vmcnt(2)" ::: "memory"); }
    else    { asm volatile("s_waitcnt vmcnt(0)" ::: "memory"); }
    __builtin_amdgcn_s_barrier();
  }

  // epilogue: lane holds O[q][d] for d = 32*dt + 8*g4 + 4*hi + 0..3
  const float inv = 1.0f / lrow;
  unsigned short* Op = Ob + ((size_t)bI * Ss + q) * Ee + hI * 64;
#pragma unroll
  for (int dt = 0; dt < 2; ++dt)
#pragma unroll
    for (int g4 = 0; g4 < 4; ++g4) {
      ushort4 o;
      o.x = f2bf(oacc[dt][g4 * 4 + 0] * inv);
      o.y = f2bf(oacc[dt][g4 * 4 + 1] * inv);
      o.z = f2bf(oacc[dt][g4 * 4 + 2] * inv);
      o.w = f2bf(oacc[dt][g4 * 4 + 3] * inv);
      *(ushort4*)(void*)&Op[dt * 32 + g4 * 8 + hi * 4] = o;
    }
}

extern "C" void kernel_launch(void* const* d_in, const int* in_sizes, int n_in,
                              void* d_out, int out_size, void* d_ws, size_t ws_size,
                              hipStream_t stream) {
  const float* x = (const float*)d_in[0];
  const float* Wq = (const float*)d_in[1];
  const float* Wk = (const float*)d_in[2];
  const float* Wv = (const float*)d_in[3];
  const float* Wproj = (const float*)d_in[4];
  const float* bproj = (const float*)d_in[5];
  float* out = (float*)d_out;

  char* ws = (char*)d_ws;
  unsigned short* xb     = (unsigned short*)(ws);                  // 16 MiB
  unsigned short* wqkvb  = (unsigned short*)(ws + (16u << 20));    //  6 MiB
  unsigned short* wprojb = (unsigned short*)(ws + (22u << 20));    //  2 MiB
  unsigned short* Qb     = (unsigned short*)(ws + (24u << 20));    // 16 MiB
  unsigned short* Kb     = (unsigned short*)(ws + (40u << 20));    // 16 MiB
  unsigned short* Vtb    = (unsigned short*)(ws + (56u << 20));    // 16 MiB
  unsigned short* Obuf   = (unsigned short*)(ws + (72u << 20));    // 16 MiB (88 total)

  cvt_fused<<<9984, 256, 0, stream>>>(x, Wproj, Wq, Wk, Wv, xb, wprojb, wqkvb);
  gemm_qkv<<<dim3(Nqkv / 128, Mq / 128), 256, 0, stream>>>(
      xb, wqkvb, Qb, Kb, Vtb, Kd);
  attn<<<512, 512, 0, stream>>>(Qb, Kb, Vtb, Obuf);
  gemm_proj<<<dim3(Ee / 128, Mq / 128), 256, 0, stream>>>(
      Obuf, wprojb, out, bproj, Ee, Kd);
}